// Round 2
// baseline (174.982 us; speedup 1.0000x reference)
//
#include <hip/hip_runtime.h>
#include <cstdint>

// Problem constants (B,S,H,D from reference)
#define BB 4
#define SS 2048
#define HH 8
#define DD 64
#define CC 64          // chunk length
#define NCK (SS/CC)    // 32 chunks
#define BHH (BB*HH)    // 32

__device__ __forceinline__ float elu1(float x) {
    // elu(x)+1 : x>0 ? x+1 : exp(x)
    return x > 0.f ? x + 1.f : __expf(x);
}

// XOR bank swizzle for 64-col row-major LDS tiles: avoids bank conflicts on
// lane-varying-row reads without +1 padding (keeps total static LDS at 64KB).
#define SWZ(r,c) (((r) * DD) + (((c) ^ ((r) & 31))))

// ---------------------------------------------------------------------------
// Kernel 1: per-chunk KV outer-product sums.
// grid = BHH*NCK blocks (1024), 256 threads.
// kvws[blk][d][t] = sum_{s in chunk} (elu(k)+1)*scale * v  outer product
// ---------------------------------------------------------------------------
__global__ __launch_bounds__(256) void kv_chunk_kernel(
    const float* __restrict__ qk, const float* __restrict__ v,
    float* __restrict__ kvws)
{
    const int blk = blockIdx.x;
    const int bh = blk / NCK, c = blk % NCK;
    const int b = bh / HH, h = bh % HH;
    const int s0 = c * CC;

    __shared__ float kb[CC * DD];
    __shared__ float vb[CC * DD];

    for (int i = threadIdx.x; i < CC * DD; i += 256) {
        const int s = i >> 6, d = i & 63;
        const float kraw = qk[(((size_t)(b * SS + s0 + s) * 2 + 1) * HH + h) * DD + d];
        kb[i] = elu1(kraw) * 0.125f;   // scale = 1/sqrt(64)
        vb[i] = v[((size_t)(b * SS + s0 + s) * HH + h) * DD + d];
    }
    __syncthreads();

    const int ty = threadIdx.x >> 4;   // d-tile: rows ty*4..ty*4+3
    const int tx = threadIdx.x & 15;   // t-tile: cols tx*4..tx*4+3

    float acc[4][4] = {};
    for (int s = 0; s < CC; ++s) {
        float kr[4], vr[4];
#pragma unroll
        for (int i = 0; i < 4; ++i) {
            kr[i] = kb[s * DD + ty * 4 + i];   // row-fixed read: conflict-free
            vr[i] = vb[s * DD + tx * 4 + i];
        }
#pragma unroll
        for (int i = 0; i < 4; ++i)
#pragma unroll
            for (int j = 0; j < 4; ++j)
                acc[i][j] += kr[i] * vr[j];
    }

    float* dst = kvws + (size_t)blk * (DD * DD);
#pragma unroll
    for (int i = 0; i < 4; ++i) {
        float4 t = make_float4(acc[i][0], acc[i][1], acc[i][2], acc[i][3]);
        *reinterpret_cast<float4*>(dst + (ty * 4 + i) * DD + tx * 4) = t;
    }
}

// ---------------------------------------------------------------------------
// Kernel 2: in-place exclusive prefix sum over chunks, per (b,h) and matrix
// element. grid = BHH*16 (512), 256 threads; each thread owns one of the 4096
// matrix entries. Loads all 32 chunk values first (independent, pipelined),
// then scans in registers.
// ---------------------------------------------------------------------------
__global__ __launch_bounds__(256) void prefix_kernel(float* __restrict__ kvws)
{
    const int bh = blockIdx.x >> 4, part = blockIdx.x & 15;
    const int e = part * 256 + threadIdx.x;
    float* p = kvws + (size_t)bh * NCK * (DD * DD) + e;

    float vals[NCK];
#pragma unroll
    for (int c = 0; c < NCK; ++c) vals[c] = p[(size_t)c * (DD * DD)];
    float run = 0.f;
#pragma unroll
    for (int c = 0; c < NCK; ++c) {
        const float t = vals[c];
        p[(size_t)c * (DD * DD)] = run;   // exclusive
        run += t;
    }
}

// ---------------------------------------------------------------------------
// Kernel 3: per-chunk output.
// out[s] = (Q @ S_excl + causal(Q K^T) @ V) * norm[s]
// grid = BHH*NCK (1024), 256 threads. LDS: q,k,v,state/A = 4 x 16KB = 64KB.
// ---------------------------------------------------------------------------
__global__ __launch_bounds__(256) void out_kernel(
    const float* __restrict__ qk, const float* __restrict__ v,
    const float* __restrict__ nrm, const float* __restrict__ offset,
    const float* __restrict__ kvws, float* __restrict__ out)
{
    const int blk = blockIdx.x;
    const int bh = blk / NCK, c = blk % NCK;
    const int b = bh / HH, h = bh % HH;
    const int s0 = c * CC;

    __shared__ float qb[CC * DD];
    __shared__ float kb[CC * DD];
    __shared__ float vb[CC * DD];
    __shared__ float sb[DD * DD];   // state, later reused for masked A

    const float* st = kvws + (size_t)blk * (DD * DD);
    for (int i = threadIdx.x; i < CC * DD; i += 256) {
        const int s = i >> 6, d = i & 63;
        const float qraw = qk[(((size_t)(b * SS + s0 + s) * 2 + 0) * HH + h) * DD + d];
        const float kraw = qk[(((size_t)(b * SS + s0 + s) * 2 + 1) * HH + h) * DD + d];
        qb[SWZ(s, d)] = elu1(qraw);
        kb[SWZ(s, d)] = elu1(kraw) * 0.125f;
        vb[SWZ(s, d)] = v[((size_t)(b * SS + s0 + s) * HH + h) * DD + d];
        sb[SWZ(s, d)] = st[i];   // here 's' is the state's d-row index
    }
    __syncthreads();

    const int ty = threadIdx.x >> 4;   // out rows s = ty*4..+3
    const int tx = threadIdx.x & 15;   // out cols t = tx*4..+3

    // Phase 2: acc = Q @ S_excl
    float acc[4][4] = {};
    for (int d = 0; d < DD; ++d) {
        float qr[4], sr[4];
#pragma unroll
        for (int i = 0; i < 4; ++i) {
            qr[i] = qb[SWZ(ty * 4 + i, d)];
            sr[i] = sb[SWZ(d, tx * 4 + i)];
        }
#pragma unroll
        for (int i = 0; i < 4; ++i)
#pragma unroll
            for (int j = 0; j < 4; ++j)
                acc[i][j] += qr[i] * sr[j];
    }

    // Phase 3: A tile = (Q K^T) * scale (scale folded into kb)
    float a[4][4] = {};
    for (int d = 0; d < DD; ++d) {
        float qr[4], kr[4];
#pragma unroll
        for (int i = 0; i < 4; ++i) {
            qr[i] = qb[SWZ(ty * 4 + i, d)];
            kr[i] = kb[SWZ(tx * 4 + i, d)];
        }
#pragma unroll
        for (int i = 0; i < 4; ++i)
#pragma unroll
            for (int j = 0; j < 4; ++j)
                a[i][j] += qr[i] * kr[j];
    }

    __syncthreads();   // all reads of sb(state) complete
    // store causal-masked A over sb: rows = query s, cols = key s2, keep s2<=s
#pragma unroll
    for (int i = 0; i < 4; ++i)
#pragma unroll
        for (int j = 0; j < 4; ++j)
            sb[SWZ(ty * 4 + i, tx * 4 + j)] = (tx * 4 + j <= ty * 4 + i) ? a[i][j] : 0.f;
    __syncthreads();

    // Phase 4: acc += A @ V
    for (int s2 = 0; s2 < CC; ++s2) {
        float ar[4], vr[4];
#pragma unroll
        for (int i = 0; i < 4; ++i) {
            ar[i] = sb[SWZ(ty * 4 + i, s2)];
            vr[i] = vb[SWZ(s2, tx * 4 + i)];
        }
#pragma unroll
        for (int i = 0; i < 4; ++i)
#pragma unroll
            for (int j = 0; j < 4; ++j)
                acc[i][j] += ar[i] * vr[j];
    }

    // Finalize: norm = exp(-softplus(n+off)) = 1/(1+exp(n+off))
    const float off = offset[h];
#pragma unroll
    for (int i = 0; i < 4; ++i) {
        const int s = s0 + ty * 4 + i;
        const float nv = nrm[(size_t)(b * SS + s) * HH + h] + off;
        const float norm = 1.f / (1.f + __expf(nv));
        float4 o = make_float4(acc[i][0] * norm, acc[i][1] * norm,
                               acc[i][2] * norm, acc[i][3] * norm);
        *reinterpret_cast<float4*>(out + ((size_t)(b * SS + s) * HH + h) * DD + tx * 4) = o;
    }
}

// ---------------------------------------------------------------------------
extern "C" void kernel_launch(void* const* d_in, const int* in_sizes, int n_in,
                              void* d_out, int out_size, void* d_ws, size_t ws_size,
                              hipStream_t stream) {
    const float* qk     = (const float*)d_in[0];
    const float* v      = (const float*)d_in[1];
    const float* nrm    = (const float*)d_in[2];
    const float* offset = (const float*)d_in[3];
    float* out  = (float*)d_out;
    float* kvws = (float*)d_ws;   // BHH*NCK*64*64 floats = 16.78 MB

    kv_chunk_kernel<<<dim3(BHH * NCK), dim3(256), 0, stream>>>(qk, v, kvws);
    prefix_kernel<<<dim3(BHH * 16), dim3(256), 0, stream>>>(kvws);
    out_kernel<<<dim3(BHH * NCK), dim3(256), 0, stream>>>(qk, v, nrm, offset, kvws, out);
}

// Round 3
// 125.080 us; speedup vs baseline: 1.3990x; 1.3990x over previous
//
#include <hip/hip_runtime.h>
#include <cstdint>

// Problem constants (B,S,H,D from reference)
#define BB 4
#define SS 2048
#define HH 8
#define DD 64
#define CC 64          // chunk length
#define NCK (SS/CC)    // 32 chunks
#define BHH (BB*HH)    // 32

typedef __attribute__((ext_vector_type(8))) short  short8;   // 8 bf16 (MFMA A/B frag)
typedef __attribute__((ext_vector_type(4))) float  f32x4;    // MFMA C/D frag
typedef __attribute__((ext_vector_type(4))) unsigned short us4;

__device__ __forceinline__ float elu1(float x) {
    return x > 0.f ? x + 1.f : __expf(x);
}
// fp32 -> bf16 RNE
__device__ __forceinline__ unsigned short f2bf(float f) {
    unsigned int u = __float_as_uint(f);
    u += 0x7FFFu + ((u >> 16) & 1u);
    return (unsigned short)(u >> 16);
}
// XOR swizzle for [64][64] bf16 LDS tile (row = 128B): spread 16B units so
// 16-lane row-varying b128 fragment reads hit the 8-cycle bank floor.
__device__ __forceinline__ int swz(int r, int c) { return r * 64 + (c ^ ((r & 7) << 3)); }

// ---------------------------------------------------------------------------
// Kernel 1: per-chunk KV sums, written T-MAJOR: kvws[blk][t][d] = S^T[t][d]
//           = sum_s v[s][t] * (elu1(k[s][d]) * scale)
// grid = 1024 blocks, 256 threads. fp32 accumulation (exact state).
// ---------------------------------------------------------------------------
__global__ __launch_bounds__(256) void kv_chunk_kernel(
    const float* __restrict__ qk, const float* __restrict__ v,
    float* __restrict__ kvws)
{
    const int blk = blockIdx.x;
    const int bh = blk / NCK, c = blk % NCK;
    const int b = bh / HH, h = bh % HH;
    const int s0 = c * CC;

    __shared__ float kb[CC * DD];
    __shared__ float vb[CC * DD];

    for (int i = threadIdx.x; i < CC * DD; i += 256) {
        const int s = i >> 6, d = i & 63;
        const float kraw = qk[(((size_t)(b * SS + s0 + s) * 2 + 1) * HH + h) * DD + d];
        kb[i] = elu1(kraw) * 0.125f;   // scale = 1/sqrt(64)
        vb[i] = v[((size_t)(b * SS + s0 + s) * HH + h) * DD + d];
    }
    __syncthreads();

    const int ty = threadIdx.x >> 4;   // t rows: ty*4..+3
    const int tx = threadIdx.x & 15;   // d cols: tx*4..+3

    float acc[4][4] = {};
    for (int s = 0; s < CC; ++s) {
        float vr[4], kr[4];
#pragma unroll
        for (int i = 0; i < 4; ++i) {
            vr[i] = vb[s * DD + ty * 4 + i];
            kr[i] = kb[s * DD + tx * 4 + i];
        }
#pragma unroll
        for (int i = 0; i < 4; ++i)
#pragma unroll
            for (int j = 0; j < 4; ++j)
                acc[i][j] += vr[i] * kr[j];
    }

    float* dst = kvws + (size_t)blk * (DD * DD);
#pragma unroll
    for (int i = 0; i < 4; ++i) {
        float4 t = make_float4(acc[i][0], acc[i][1], acc[i][2], acc[i][3]);
        *reinterpret_cast<float4*>(dst + (ty * 4 + i) * DD + tx * 4) = t;  // [t][d]
    }
}

// ---------------------------------------------------------------------------
// Kernel 2: in-place exclusive prefix sum over chunks (layout-agnostic).
// ---------------------------------------------------------------------------
__global__ __launch_bounds__(256) void prefix_kernel(float* __restrict__ kvws)
{
    const int bh = blockIdx.x >> 4, part = blockIdx.x & 15;
    const int e = part * 256 + threadIdx.x;
    float* p = kvws + (size_t)bh * NCK * (DD * DD) + e;

    float vals[NCK];
#pragma unroll
    for (int c = 0; c < NCK; ++c) vals[c] = p[(size_t)c * (DD * DD)];
    float run = 0.f;
#pragma unroll
    for (int c = 0; c < NCK; ++c) {
        const float t = vals[c];
        p[(size_t)c * (DD * DD)] = run;   // exclusive
        run += t;
    }
}

// ---------------------------------------------------------------------------
// Kernel 3 (MFMA): out[s][t] = norm(s) * ( Q@S_excl + causal(Q K^T)@V )
// grid = 1024 blocks, 256 threads (4 waves; wave w owns s-rows w*16..+15).
// LDS: qb[s][d], kb[s2][d], st = S^T[t][d] (reused as As[s][s2]) — 24 KB bf16.
// V B-fragments loaded directly from global (avoids LDS transpose).
// ---------------------------------------------------------------------------
__global__ __launch_bounds__(256) void out_kernel(
    const float* __restrict__ qk, const float* __restrict__ v,
    const float* __restrict__ nrm, const float* __restrict__ offset,
    const float* __restrict__ kvws, float* __restrict__ out)
{
    const int blk = blockIdx.x;
    const int bh = blk / NCK, c = blk % NCK;
    const int b = bh / HH, h = bh % HH;
    const int s0 = c * CC;

    __shared__ unsigned short qb[CC * DD];   // q rows s, cols d (swizzled)
    __shared__ unsigned short kb[CC * DD];   // k rows s2, cols d (swizzled)
    __shared__ unsigned short st[CC * DD];   // S^T rows t, cols d; reused as As[s][s2]

    const int tid = threadIdx.x;
    const float* stg = kvws + (size_t)blk * (DD * DD);

    // ---- stage: q (elu1), k (elu1*scale), S^T (bf16) ----
    for (int it = tid; it < 1024; it += 256) {
        const int r = it >> 4;            // row 0..63
        const int c0 = (it & 15) * 4;     // col 0..60
        const size_t qrow = (((size_t)(b * SS + s0 + r) * 2 + 0) * HH + h) * DD;
        const size_t krow = (((size_t)(b * SS + s0 + r) * 2 + 1) * HH + h) * DD;

        float4 fq = *reinterpret_cast<const float4*>(qk + qrow + c0);
        us4 uq; uq.x = f2bf(elu1(fq.x)); uq.y = f2bf(elu1(fq.y));
                uq.z = f2bf(elu1(fq.z)); uq.w = f2bf(elu1(fq.w));
        *reinterpret_cast<us4*>(&qb[swz(r, c0)]) = uq;

        float4 fk = *reinterpret_cast<const float4*>(qk + krow + c0);
        us4 uk; uk.x = f2bf(elu1(fk.x) * 0.125f); uk.y = f2bf(elu1(fk.y) * 0.125f);
                uk.z = f2bf(elu1(fk.z) * 0.125f); uk.w = f2bf(elu1(fk.w) * 0.125f);
        *reinterpret_cast<us4*>(&kb[swz(r, c0)]) = uk;

        float4 fs = *reinterpret_cast<const float4*>(stg + r * DD + c0);
        us4 us_; us_.x = f2bf(fs.x); us_.y = f2bf(fs.y);
                 us_.z = f2bf(fs.z); us_.w = f2bf(fs.w);
        *reinterpret_cast<us4*>(&st[swz(r, c0)]) = us_;
    }
    __syncthreads();

    const int lane  = tid & 63;
    const int wid   = tid >> 6;          // wave id 0..3
    const int lr    = lane & 15;         // A/B frag row select; C frag col
    const int lk    = (lane >> 4) * 8;   // k offset within 32-block
    const int mbase = wid * 16;          // wave's s-row base
    const int crow  = (lane >> 4) * 4;   // C frag row base (+reg)

    // Q A-fragments (reused by phases A and B)
    short8 aq0 = *reinterpret_cast<const short8*>(&qb[swz(mbase + lr, lk)]);
    short8 aq1 = *reinterpret_cast<const short8*>(&qb[swz(mbase + lr, 32 + lk)]);

    f32x4 acc[4] = {};   // O accumulators, n-tiles 0..3
    f32x4 as4[4] = {};   // QK^T score tiles

#pragma unroll
    for (int kk = 0; kk < 2; ++kk) {
        const short8 aq = kk ? aq1 : aq0;
#pragma unroll
        for (int nb = 0; nb < 4; ++nb) {
            // Phase A: B = S (from S^T rows t), k = d
            short8 bs = *reinterpret_cast<const short8*>(&st[swz(nb * 16 + lr, kk * 32 + lk)]);
            acc[nb] = __builtin_amdgcn_mfma_f32_16x16x32_bf16(aq, bs, acc[nb], 0, 0, 0);
            // Phase B: B = K^T (from K rows s2), k = d
            short8 bk = *reinterpret_cast<const short8*>(&kb[swz(nb * 16 + lr, kk * 32 + lk)]);
            as4[nb] = __builtin_amdgcn_mfma_f32_16x16x32_bf16(aq, bk, as4[nb], 0, 0, 0);
        }
    }

    __syncthreads();   // everyone done reading st (state)

    // write causal-masked As (bf16) into st as As[s][s2]
#pragma unroll
    for (int nb = 0; nb < 4; ++nb) {
#pragma unroll
        for (int r = 0; r < 4; ++r) {
            const int s_loc = mbase + crow + r;
            const int s2    = nb * 16 + lr;
            const float val = (s2 <= s_loc) ? as4[nb][r] : 0.f;
            st[swz(s_loc, s2)] = f2bf(val);
        }
    }
    __syncthreads();

    // Phase C: O += As @ V ; A from LDS, B (V) direct from global (column loads)
    short8 aA0 = *reinterpret_cast<const short8*>(&st[swz(mbase + lr, lk)]);
    short8 aA1 = *reinterpret_cast<const short8*>(&st[swz(mbase + lr, 32 + lk)]);
    const float* vbase = v + ((size_t)(b * SS + s0) * HH + h) * DD;  // row stride HH*DD

#pragma unroll
    for (int kk = 0; kk < 2; ++kk) {
        const short8 aa = kk ? aA1 : aA0;
        short8 bvf[4];
#pragma unroll
        for (int nb = 0; nb < 4; ++nb) {
            const float* vp = vbase + (size_t)(kk * 32 + lk) * (HH * DD) + nb * 16 + lr;
#pragma unroll
            for (int j = 0; j < 8; ++j)
                bvf[nb][j] = (short)f2bf(vp[(size_t)j * (HH * DD)]);
        }
#pragma unroll
        for (int nb = 0; nb < 4; ++nb)
            acc[nb] = __builtin_amdgcn_mfma_f32_16x16x32_bf16(aa, bvf[nb], acc[nb], 0, 0, 0);
    }

    // epilogue: norm = 1/(1+exp(n+off)); C frag: row s = mbase+crow+r, col t = nb*16+lr
    const float off = offset[h];
    float nv[4];
#pragma unroll
    for (int r = 0; r < 4; ++r) {
        const int s = s0 + mbase + crow + r;
        nv[r] = 1.f / (1.f + __expf(nrm[(size_t)(b * SS + s) * HH + h] + off));
    }
#pragma unroll
    for (int nb = 0; nb < 4; ++nb) {
#pragma unroll
        for (int r = 0; r < 4; ++r) {
            const int s = s0 + mbase + crow + r;
            out[((size_t)(b * SS + s) * HH + h) * DD + nb * 16 + lr] = acc[nb][r] * nv[r];
        }
    }
}

// ---------------------------------------------------------------------------
extern "C" void kernel_launch(void* const* d_in, const int* in_sizes, int n_in,
                              void* d_out, int out_size, void* d_ws, size_t ws_size,
                              hipStream_t stream) {
    const float* qk     = (const float*)d_in[0];
    const float* v      = (const float*)d_in[1];
    const float* nrm    = (const float*)d_in[2];
    const float* offset = (const float*)d_in[3];
    float* out  = (float*)d_out;
    float* kvws = (float*)d_ws;   // 32*32*64*64 floats = 16.78 MB

    kv_chunk_kernel<<<dim3(BHH * NCK), dim3(256), 0, stream>>>(qk, v, kvws);
    prefix_kernel<<<dim3(BHH * 16), dim3(256), 0, stream>>>(kvws);
    out_kernel<<<dim3(BHH * NCK), dim3(256), 0, stream>>>(qk, v, nrm, offset, kvws, out);
}

// Round 4
// 110.348 us; speedup vs baseline: 1.5857x; 1.1335x over previous
//
#include <hip/hip_runtime.h>
#include <cstdint>

// Problem constants (B,S,H,D from reference)
#define BB 4
#define SS 2048
#define HH 8
#define DD 64
#define CC 64          // chunk length
#define NCK (SS/CC)    // 32 chunks
#define BHH (BB*HH)    // 32

typedef __attribute__((ext_vector_type(8))) short  short8;   // 8 bf16 (MFMA A/B frag)
typedef __attribute__((ext_vector_type(4))) float  f32x4;    // MFMA C/D frag
typedef __attribute__((ext_vector_type(4))) unsigned short us4;

__device__ __forceinline__ float elu1(float x) {
    return x > 0.f ? x + 1.f : __expf(x);
}
// fp32 -> bf16 RNE
__device__ __forceinline__ unsigned short f2bf(float f) {
    unsigned int u = __float_as_uint(f);
    u += 0x7FFFu + ((u >> 16) & 1u);
    return (unsigned short)(u >> 16);
}
__device__ __forceinline__ float bf2f(unsigned short h) {
    return __uint_as_float(((unsigned int)h) << 16);
}
// XOR swizzle for [64][64] bf16 LDS tiles (rows 128B): spreads 16B units so
// row-varying b128 fragment reads avoid same-bank serialization.
#define SWZ(r,c) ((r) * DD + ((c) ^ (((r) & 7) << 3)))

// 4x4 lane-transpose. Pre: lane with bits (b1,b0) from masks (M1,M0) holds
// v[e] = M[g][e], g=(b1<<1)|b0. Post: v[e] = M[e][g]. 4 shfl_xor total.
template<int M0, int M1>
__device__ __forceinline__ void xpose4(float v[4], int lane) {
    {
        const bool hi = (lane & M0) != 0;
        float x0 = hi ? v[0] : v[1];
        float x1 = hi ? v[2] : v[3];
        float r0 = __shfl_xor(x0, M0);
        float r1 = __shfl_xor(x1, M0);
        if (hi) { v[0] = r0; v[2] = r1; } else { v[1] = r0; v[3] = r1; }
    }
    {
        const bool hi = (lane & M1) != 0;
        float x0 = hi ? v[0] : v[2];
        float x1 = hi ? v[1] : v[3];
        float r0 = __shfl_xor(x0, M1);
        float r1 = __shfl_xor(x1, M1);
        if (hi) { v[0] = r0; v[1] = r1; } else { v[2] = r0; v[3] = r1; }
    }
}

__device__ __forceinline__ unsigned long long pack4bf(const float v[4]) {
    unsigned long long r;
    r  = (unsigned long long)f2bf(v[0]);
    r |= (unsigned long long)f2bf(v[1]) << 16;
    r |= (unsigned long long)f2bf(v[2]) << 32;
    r |= (unsigned long long)f2bf(v[3]) << 48;
    return r;
}

// ---------------------------------------------------------------------------
// Kernel 1 (MFMA): per-chunk  S^T[t][d] = sum_s v[s][t] * (elu1(k[s][d])/8)
// Also emits V^T bf16 chunk tiles for K3's PV step.
// grid = 1024, 256 threads. LDS: kT + vT (bf16, swizzled) = 16 KB.
// ---------------------------------------------------------------------------
__global__ __launch_bounds__(256) void kv_chunk_kernel(
    const float* __restrict__ qk, const float* __restrict__ v,
    unsigned short* __restrict__ Sws, unsigned short* __restrict__ vtws)
{
    const int blk = blockIdx.x;
    const int bh = blk / NCK, c = blk % NCK;
    const int b = bh / HH, h = bh % HH;
    const int s0 = c * CC;

    __shared__ unsigned short kT[CC * DD];   // [d][s] swizzled
    __shared__ unsigned short vT[CC * DD];   // [t][s] swizzled

    const int tid = threadIdx.x, lane = tid & 63;

    // ---- stage with in-wave 4x4 transpose (lanes l, l+16, l+32, l+48) ----
#pragma unroll
    for (int iter = 0; iter < 4; ++iter) {
        const int it = iter * 256 + tid;
        const int r = it >> 4, c0 = (it & 15) * 4;   // input row s=r, cols c0..c0+3
        const int g = lane >> 4;                     // row-within-4x4-block
        const int rb = r - g;                        // block row base (4-aligned)

        float4 fk = *reinterpret_cast<const float4*>(
            qk + (((size_t)(b * SS + s0 + r) * 2 + 1) * HH + h) * DD + c0);
        float kv4[4] = { elu1(fk.x) * 0.125f, elu1(fk.y) * 0.125f,
                         elu1(fk.z) * 0.125f, elu1(fk.w) * 0.125f };
        xpose4<16, 32>(kv4, lane);                   // lane now: col d=c0+g, rows rb..rb+3
        *reinterpret_cast<unsigned long long*>(&kT[SWZ(c0 + g, rb)]) = pack4bf(kv4);

        float4 fv = *reinterpret_cast<const float4*>(
            v + ((size_t)(b * SS + s0 + r) * HH + h) * DD + c0);
        float vv4[4] = { fv.x, fv.y, fv.z, fv.w };
        xpose4<16, 32>(vv4, lane);
        *reinterpret_cast<unsigned long long*>(&vT[SWZ(c0 + g, rb)]) = pack4bf(vv4);
    }
    __syncthreads();

    // ---- dump V^T (unswizzled, linear [t][s]) to global for K3 ----
#pragma unroll
    for (int j = 0; j < 2; ++j) {
        const int slot = j * 256 + tid;              // 512 b128 slots
        const int r = slot >> 3, c0 = (slot & 7) * 8;
        short8 val = *reinterpret_cast<const short8*>(&vT[SWZ(r, c0)]);
        *reinterpret_cast<short8*>(vtws + (size_t)blk * 4096 + slot * 8) = val;
    }

    // ---- MFMA: C[t][d] = sum_s vT[t,s] * kT[d,s] ----
    const int lr = lane & 15, lk = (lane >> 4) * 8;
    const int wid = tid >> 6, mbase = wid * 16;
    f32x4 acc[4] = {};
#pragma unroll
    for (int kk = 0; kk < 2; ++kk) {
        short8 a = *reinterpret_cast<const short8*>(&vT[SWZ(mbase + lr, kk * 32 + lk)]);
#pragma unroll
        for (int nb = 0; nb < 4; ++nb) {
            short8 bk = *reinterpret_cast<const short8*>(&kT[SWZ(nb * 16 + lr, kk * 32 + lk)]);
            acc[nb] = __builtin_amdgcn_mfma_f32_16x16x32_bf16(a, bk, acc[nb], 0, 0, 0);
        }
    }

    // ---- C write: pack along d via 4x4 transpose on lane bits 0,1 ----
    const int crow = (lane >> 4) * 4;
#pragma unroll
    for (int nb = 0; nb < 4; ++nb) {
        float cv[4] = { acc[nb][0], acc[nb][1], acc[nb][2], acc[nb][3] };
        xpose4<1, 2>(cv, lane);                      // lane: row t=crow+(lane&3), 4 d-cols
        const int t  = mbase + crow + (lane & 3);
        const int d0 = nb * 16 + (lr & ~3);
        *reinterpret_cast<unsigned long long*>(
            Sws + (size_t)blk * 4096 + t * 64 + d0) = pack4bf(cv);
    }
}

// ---------------------------------------------------------------------------
// Kernel 2: exclusive prefix over chunks, bf16 in/out, fp32 running sum.
// ---------------------------------------------------------------------------
__global__ __launch_bounds__(256) void prefix_kernel(unsigned short* __restrict__ Sws)
{
    const int bh = blockIdx.x >> 4, part = blockIdx.x & 15;
    const int e = part * 256 + threadIdx.x;
    unsigned short* p = Sws + (size_t)bh * NCK * 4096 + e;

    unsigned short vals[NCK];
#pragma unroll
    for (int c = 0; c < NCK; ++c) vals[c] = p[(size_t)c * 4096];
    float run = 0.f;
#pragma unroll
    for (int c = 0; c < NCK; ++c) {
        p[(size_t)c * 4096] = f2bf(run);   // exclusive
        run += bf2f(vals[c]);
    }
}

// ---------------------------------------------------------------------------
// Kernel 3 (MFMA): out[s][t] = norm(s) * ( Q@S_excl + causal(Q K^T)@V )
// grid = 1024, 256 threads (4 waves). LDS: qb, kb, st(S^T->As), vt = 32 KB.
// ---------------------------------------------------------------------------
__global__ __launch_bounds__(256) void out_kernel(
    const float* __restrict__ qk, const float* __restrict__ nrm,
    const float* __restrict__ offset,
    const unsigned short* __restrict__ Sws, const unsigned short* __restrict__ vtws,
    float* __restrict__ out)
{
    const int blk = blockIdx.x;
    const int bh = blk / NCK, c = blk % NCK;
    const int b = bh / HH, h = bh % HH;
    const int s0 = c * CC;

    __shared__ unsigned short qb[CC * DD];   // [s][d] swz
    __shared__ unsigned short kb[CC * DD];   // [s2][d] swz
    __shared__ unsigned short st[CC * DD];   // S^T [t][d] swz; reused as As[s][s2]
    __shared__ unsigned short vt[CC * DD];   // V^T [t][s2] swz

    const int tid = threadIdx.x;

    // ---- stage q,k (fp32 -> elu1 -> bf16) ----
#pragma unroll
    for (int iter = 0; iter < 4; ++iter) {
        const int it = iter * 256 + tid;
        const int r = it >> 4, c0 = (it & 15) * 4;
        const size_t qrow = (((size_t)(b * SS + s0 + r) * 2 + 0) * HH + h) * DD;
        const size_t krow = (((size_t)(b * SS + s0 + r) * 2 + 1) * HH + h) * DD;

        float4 fq = *reinterpret_cast<const float4*>(qk + qrow + c0);
        us4 uq; uq.x = f2bf(elu1(fq.x)); uq.y = f2bf(elu1(fq.y));
                uq.z = f2bf(elu1(fq.z)); uq.w = f2bf(elu1(fq.w));
        *reinterpret_cast<us4*>(&qb[SWZ(r, c0)]) = uq;

        float4 fk = *reinterpret_cast<const float4*>(qk + krow + c0);
        us4 uk; uk.x = f2bf(elu1(fk.x) * 0.125f); uk.y = f2bf(elu1(fk.y) * 0.125f);
                uk.z = f2bf(elu1(fk.z) * 0.125f); uk.w = f2bf(elu1(fk.w) * 0.125f);
        *reinterpret_cast<us4*>(&kb[SWZ(r, c0)]) = uk;
    }
    // ---- stage S^T and V^T (bf16 b128 copies into swizzled LDS) ----
#pragma unroll
    for (int j = 0; j < 2; ++j) {
        const int slot = j * 256 + tid;
        const int r = slot >> 3, c0 = (slot & 7) * 8;
        *reinterpret_cast<short8*>(&st[SWZ(r, c0)]) =
            *reinterpret_cast<const short8*>(Sws + (size_t)blk * 4096 + slot * 8);
        *reinterpret_cast<short8*>(&vt[SWZ(r, c0)]) =
            *reinterpret_cast<const short8*>(vtws + (size_t)blk * 4096 + slot * 8);
    }
    __syncthreads();

    const int lane  = tid & 63;
    const int wid   = tid >> 6;
    const int lr    = lane & 15;
    const int lk    = (lane >> 4) * 8;
    const int mbase = wid * 16;
    const int crow  = (lane >> 4) * 4;

    short8 aq0 = *reinterpret_cast<const short8*>(&qb[SWZ(mbase + lr, lk)]);
    short8 aq1 = *reinterpret_cast<const short8*>(&qb[SWZ(mbase + lr, 32 + lk)]);

    f32x4 acc[4] = {};   // O accumulators
    f32x4 as4[4] = {};   // QK^T scores

#pragma unroll
    for (int kk = 0; kk < 2; ++kk) {
        const short8 aq = kk ? aq1 : aq0;
#pragma unroll
        for (int nb = 0; nb < 4; ++nb) {
            short8 bs = *reinterpret_cast<const short8*>(&st[SWZ(nb * 16 + lr, kk * 32 + lk)]);
            acc[nb] = __builtin_amdgcn_mfma_f32_16x16x32_bf16(aq, bs, acc[nb], 0, 0, 0);
            short8 bk = *reinterpret_cast<const short8*>(&kb[SWZ(nb * 16 + lr, kk * 32 + lk)]);
            as4[nb] = __builtin_amdgcn_mfma_f32_16x16x32_bf16(aq, bk, as4[nb], 0, 0, 0);
        }
    }

    __syncthreads();   // st (state) fully consumed

    // causal-masked As (bf16) into st as As[s][s2]
#pragma unroll
    for (int nb = 0; nb < 4; ++nb) {
#pragma unroll
        for (int r = 0; r < 4; ++r) {
            const int s_loc = mbase + crow + r;
            const int s2    = nb * 16 + lr;
            const float val = (s2 <= s_loc) ? as4[nb][r] : 0.f;
            st[SWZ(s_loc, s2)] = f2bf(val);
        }
    }
    __syncthreads();

    // Phase C: O += As @ V  (B = V^T rows t from LDS)
    short8 aA0 = *reinterpret_cast<const short8*>(&st[SWZ(mbase + lr, lk)]);
    short8 aA1 = *reinterpret_cast<const short8*>(&st[SWZ(mbase + lr, 32 + lk)]);
#pragma unroll
    for (int kk = 0; kk < 2; ++kk) {
        const short8 aa = kk ? aA1 : aA0;
#pragma unroll
        for (int nb = 0; nb < 4; ++nb) {
            short8 bv = *reinterpret_cast<const short8*>(&vt[SWZ(nb * 16 + lr, kk * 32 + lk)]);
            acc[nb] = __builtin_amdgcn_mfma_f32_16x16x32_bf16(aa, bv, acc[nb], 0, 0, 0);
        }
    }

    // epilogue
    const float off = offset[h];
    float nv[4];
#pragma unroll
    for (int r = 0; r < 4; ++r) {
        const int s = s0 + mbase + crow + r;
        nv[r] = 1.f / (1.f + __expf(nrm[(size_t)(b * SS + s) * HH + h] + off));
    }
#pragma unroll
    for (int nb = 0; nb < 4; ++nb) {
#pragma unroll
        for (int r = 0; r < 4; ++r) {
            const int s = s0 + mbase + crow + r;
            out[((size_t)(b * SS + s) * HH + h) * DD + nb * 16 + lr] = acc[nb][r] * nv[r];
        }
    }
}

// ---------------------------------------------------------------------------
extern "C" void kernel_launch(void* const* d_in, const int* in_sizes, int n_in,
                              void* d_out, int out_size, void* d_ws, size_t ws_size,
                              hipStream_t stream) {
    const float* qk     = (const float*)d_in[0];
    const float* v      = (const float*)d_in[1];
    const float* nrm    = (const float*)d_in[2];
    const float* offset = (const float*)d_in[3];
    float* out = (float*)d_out;

    unsigned short* Sws  = (unsigned short*)d_ws;            // 8.39 MB
    unsigned short* vtws = Sws + (size_t)BHH * NCK * 4096;   // 8.39 MB

    kv_chunk_kernel<<<dim3(BHH * NCK), dim3(256), 0, stream>>>(qk, v, Sws, vtws);
    prefix_kernel<<<dim3(BHH * 16), dim3(256), 0, stream>>>(Sws);
    out_kernel<<<dim3(BHH * NCK), dim3(256), 0, stream>>>(qk, nrm, offset, Sws, vtws, out);
}